// Round 2
// baseline (7225.396 us; speedup 1.0000x reference)
//
#include <hip/hip_runtime.h>

// ---------------- problem constants ----------------
#define NN      16384      // total nodes
#define TSTEPS  32
#define SG      256        // graphs
#define NE      262144
#define NPANEL  24         // 22 panels for xl@Wih (21x384 + 128) + 2 for lh@Whh (384+128)
#define GSTRIDE 524288u    // 256*2048 floats per panel partial

// ---------------- workspace layout (float offsets) ----------------
#define OFF_ENC_MEM   0u
#define OFF_ENC_SPK   2097152u
#define OFF_C1_MEM    4194304u
#define OFF_C1_SPK    6291456u     // == xl [256][8192]
#define OFF_LH        8388608u
#define OFF_LC        8519680u
#define OFF_H1_MEM    8650752u
#define OFF_H1_SPK    8716288u
#define OFF_H2_MEM    8781824u
#define OFF_H2_SPK    8782848u
#define OFF_H2_SUM    8783872u
#define ZERO_FLOATS   8784896u     // everything below here zeroed each launch
#define OFF_BASES     8784896u
#define OFF_COMB      9833472u
#define OFF_GATES     10357760u    // 256 x 2048 (unused after combine fusion; kept for layout)
#define OFF_PART      10882048u    // 24 x 256 x 2048 panel partials
#define OFF_DINV      23464960u
#define OFF_COLW      23481344u
#define FLOAT_END     23743488u
// int region (offsets from ibase)
#define IOFF_DEG      0
#define IOFF_FILL     16384
#define IOFF_ROWPTR   32768
#define IOFF_EID      49153
#define IOFF_COL      311297
#define INT_COUNT     573441

// ---------------- graph preprocessing ----------------
__global__ void k_deg(const int* __restrict__ ei, int* __restrict__ deg) {
  int e = blockIdx.x * 256 + threadIdx.x;
  if (e < NE) atomicAdd(&deg[ei[NE + e]], 1);
}

__global__ void k_dinv(const int* __restrict__ deg, float* __restrict__ dinv) {
  int n = blockIdx.x * 256 + threadIdx.x;
  if (n < NN) dinv[n] = __fdiv_rn(1.0f, __fsqrt_rn((float)(deg[n] + 1)));  // +1 self-loop
}

__global__ void k_scan(const int* __restrict__ deg, int* __restrict__ rowp) {
  __shared__ int sdata[1024];
  int tid = threadIdx.x;
  int base = tid * 16;
  int loc[16];
  int sum = 0;
  #pragma unroll
  for (int i = 0; i < 16; ++i) { loc[i] = sum; sum += deg[base + i]; }
  sdata[tid] = sum;
  __syncthreads();
  for (int off = 1; off < 1024; off <<= 1) {
    int v = 0;
    if (tid >= off) v = sdata[tid - off];
    __syncthreads();
    sdata[tid] += v;
    __syncthreads();
  }
  int excl = (tid == 0) ? 0 : sdata[tid - 1];
  #pragma unroll
  for (int i = 0; i < 16; ++i) rowp[base + i] = excl + loc[i];
  if (tid == 1023) rowp[NN] = sdata[1023];
}

__global__ void k_scatter(const int* __restrict__ ei, const int* __restrict__ rowp,
                          int* __restrict__ fill, int* __restrict__ eid) {
  int e = blockIdx.x * 256 + threadIdx.x;
  if (e >= NE) return;
  int d = ei[NE + e];
  int pos = rowp[d] + atomicAdd(&fill[d], 1);
  eid[pos] = e;
}

// sort each adjacency list by EDGE ID (unique keys) -> summation order == scatter-add order
__global__ void k_sortadj(const int* __restrict__ rowp, int* __restrict__ eid,
                          const int* __restrict__ ei, const float* __restrict__ dinv,
                          int* __restrict__ col, float* __restrict__ colw) {
  int d = blockIdx.x * 256 + threadIdx.x;
  if (d >= NN) return;
  int r0 = rowp[d], r1 = rowp[d + 1];
  for (int i = r0 + 1; i < r1; ++i) {
    int key = eid[i];
    int j = i - 1;
    while (j >= r0 && eid[j] > key) { eid[j + 1] = eid[j]; --j; }
    eid[j + 1] = key;
  }
  for (int i = r0; i < r1; ++i) {
    int s = ei[eid[i]];
    col[i] = s;
    colw[i] = dinv[s];
  }
}

// ---------------- per-timestep kernels ----------------
// enc LIF (2 nodes/block; x staged through LDS to kill strided scalar loads)
__global__ __launch_bounds__(256) void k_enc(
    const float* __restrict__ x, const float* __restrict__ encW, const float* __restrict__ encB,
    float* __restrict__ enc_mem, float* __restrict__ enc_spk, int t) {
  __shared__ float xs[2][8];
  int tid = threadIdx.x;
  int nb = blockIdx.x * 2;
  if (tid < 16)
    xs[tid >> 3][tid & 7] = x[(size_t)(nb + (tid >> 3)) * 256 + (size_t)(tid & 7) * 32 + t];
  __syncthreads();
  int nl = tid >> 7, j = tid & 127;
  int idx = (nb + nl) * 128 + j;
  float dot = 0.f;
  #pragma unroll
  for (int c = 0; c < 8; ++c) dot = __fmaf_rn(xs[nl][c], encW[c * 128 + j], dot);
  float m = enc_mem[idx], s = enc_spk[idx];
  float nm = __fadd_rn(__fadd_rn(__fmul_rn(__fmul_rn(m, 0.2f), __fsub_rn(1.f, s)), dot), encB[j]);
  enc_mem[idx] = nm;
  enc_spk[idx] = nm > 0.5f ? 1.f : 0.f;
}

// bases = spk @ bases_W + b ; comb = spk @ comb_W + b
// lane = node (64/block), 32 independent channel chains per lane.
// Wave roles: w0 bases ch0-31, w1 bases ch32-63, w2 comb ch0-15, w3 comb ch16-31.
// Spike: 1 ds_read_b32/j (2-way wrap, free). Weights: lane-invariant addr -> s_load.
// Per-output chain: fma ascending j from 0, then +bias == round-3 chain (bit-exact).
__global__ __launch_bounds__(256) void k_bases_comb(
    const float* __restrict__ enc_spk,
    const float* __restrict__ basesW, const float* __restrict__ basesB,
    const float* __restrict__ combW, const float* __restrict__ combB,
    float* __restrict__ bases, float* __restrict__ comb) {
  __shared__ float sp[64 * 129];   // [node][j], pad 129 -> (n+j)%32 banks
  __shared__ float ob[64 * 65];    // bases out [node][ch], pad 65
  __shared__ float oc[64 * 33];    // comb out [node][ch], pad 33
  const int tid = threadIdx.x;
  const int nb = blockIdx.x * 64;
  // stage spikes: idx = k*256+tid -> per-wave node is constant -> conflict-free writes
  #pragma unroll 4
  for (int k = 0; k < 32; ++k) {
    int idx = k * 256 + tid;
    int n = idx >> 7, j = idx & 127;
    sp[n * 129 + j] = enc_spk[(size_t)nb * 128 + idx];
  }
  __syncthreads();
  const int lane = tid & 63;
  const int w = tid >> 6;
  const float* spn = sp + lane * 129;
  if (w < 2) {
    const int ch0 = w * 32;
    const float* Wp = basesW + ch0;
    float acc[32];
    #pragma unroll
    for (int c = 0; c < 32; ++c) acc[c] = 0.f;
    for (int j = 0; j < 128; ++j) {
      const float s = spn[j];
      const float* wr = Wp + j * 64;     // lane-invariant -> scalar loads
      #pragma unroll
      for (int c = 0; c < 32; ++c) acc[c] = __fmaf_rn(s, wr[c], acc[c]);
    }
    #pragma unroll
    for (int c = 0; c < 32; ++c) ob[lane * 65 + ch0 + c] = acc[c];
  } else {
    const int ch0 = (w - 2) * 16;
    const float* Wp = combW + ch0;
    float acc[16];
    #pragma unroll
    for (int c = 0; c < 16; ++c) acc[c] = 0.f;
    for (int j = 0; j < 128; ++j) {
      const float s = spn[j];
      const float* wr = Wp + j * 32;
      #pragma unroll
      for (int c = 0; c < 16; ++c) acc[c] = __fmaf_rn(s, wr[c], acc[c]);
    }
    #pragma unroll
    for (int c = 0; c < 16; ++c) oc[lane * 33 + ch0 + c] = acc[c];
  }
  __syncthreads();
  // coalesced stores with bias
  #pragma unroll
  for (int r = 0; r < 16; ++r) {
    int idx = r * 256 + tid;
    int n = idx >> 6, ch = idx & 63;
    bases[(size_t)(nb + n) * 64 + ch] = __fadd_rn(ob[n * 65 + ch], basesB[ch]);
  }
  #pragma unroll
  for (int r = 0; r < 8; ++r) {
    int idx = r * 256 + tid;
    int n = idx >> 5, ch = idx & 31;
    comb[(size_t)(nb + n) * 32 + ch] = __fadd_rn(oc[n * 33 + ch], combB[ch]);
  }
}

// fused: symnorm aggregation (edge-order scatter-add) -> einsum -> conv LIF -> c1 spike
__global__ __launch_bounds__(256) void k_aggconv(
    const float* __restrict__ bases, const float* __restrict__ comb,
    const float* __restrict__ dinv, const int* __restrict__ rowp,
    const int* __restrict__ col, const float* __restrict__ colw,
    const float* __restrict__ convB,
    float* __restrict__ c1_mem, float* __restrict__ c1_spk) {
  __shared__ float aggl[4][64];
  __shared__ float combl[4][32];
  int w = threadIdx.x >> 6;
  int m = threadIdx.x & 63;
  int d = blockIdx.x * 4 + w;
  float dd = dinv[d];
  int r0 = rowp[d], r1 = rowp[d + 1];
  float acc = 0.f;
  for (int r = r0; r < r1; ++r) {
    int s = col[r];
    float ew  = __fmul_rn(colw[r], dd);
    float upd = __fmul_rn(ew, bases[(size_t)s * 64 + m]);
    acc = __fadd_rn(acc, upd);
  }
  {
    float ew  = __fmul_rn(dd, dd);
    float upd = __fmul_rn(ew, bases[(size_t)d * 64 + m]);
    acc = __fadd_rn(acc, upd);
  }
  aggl[w][m] = acc;
  if (m < 32) combl[w][m] = comb[(size_t)d * 32 + m];
  __syncthreads();
  #pragma unroll
  for (int half = 0; half < 2; ++half) {
    int j = m + half * 64;
    int h = j >> 4, f = j & 15;
    float cv = 0.f;
    #pragma unroll
    for (int b = 0; b < 4; ++b)
      cv = __fadd_rn(cv, __fmul_rn(combl[w][h * 4 + b], aggl[w][b * 16 + f]));
    cv = __fadd_rn(cv, convB[j]);
    int idx = d * 128 + j;
    float cm = c1_mem[idx], cs = c1_spk[idx];
    float nm = __fadd_rn(__fmul_rn(__fmul_rn(cm, 0.2f), __fsub_rn(1.f, cs)), cv);
    c1_mem[idx] = nm;
    c1_spk[idx] = nm > 0.5f ? 1.f : 0.f;
  }
}

// one BLAS panel of the gates GEMM: part[z] = A[:, panel_z] @ B[panel_z, :]
// 128x64 tile (acc 8x4/thread), grid (32,2,24)=1536 blocks for higher occupancy.
// Per-output chain: single FMA chain ascending k within the panel (bit-exact, unchanged).
__global__ __launch_bounds__(256, 4) void k_gpanel(
    const float* __restrict__ xl, const float* __restrict__ lh,
    const float* __restrict__ Wih, const float* __restrict__ Whh,
    float* __restrict__ part) {
  __shared__ __align__(16) float Ast[16][132];   // [k][m] transposed (128 rows + pad)
  __shared__ __align__(16) float Bs[16][68];     // [k][n] (64 cols + pad)
  const int tid = threadIdx.x;
  const int tx = tid & 15, ty = tid >> 4;
  const int n0 = blockIdx.x * 64;
  const int m0 = blockIdx.y * 128;
  const int z  = blockIdx.z;

  const float* Asrc; const float* Bsrc; int lda, k0, klen;
  if (z < 22) { Asrc = xl; Bsrc = Wih; lda = 8192; k0 = z * 384; klen = (z == 21) ? 128 : 384; }
  else        { Asrc = lh; Bsrc = Whh; lda = 512;  k0 = (z == 22) ? 0 : 384; klen = (z == 22) ? 384 : 128; }

  float acc[8][4];
  #pragma unroll
  for (int i = 0; i < 8; ++i)
    #pragma unroll
    for (int j = 0; j < 4; ++j) acc[i][j] = 0.f;

  const int arow = tid >> 1;            // 0..127
  const int acol = (tid & 1) * 8;       // 0 or 8
  const int brow = tid >> 4;            // 0..15
  const int bcol = (tid & 15) * 4;      // 0..60

  const int nkt = klen >> 4;
  for (int kt = 0; kt < nkt; ++kt) {
    const int kb = k0 + (kt << 4);
    __syncthreads();
    {   // A tile -> transposed LDS
      const float* src = Asrc + (size_t)(m0 + arow) * lda + kb + acol;
      const float4 v0 = ((const float4*)src)[0];
      const float4 v1 = ((const float4*)src)[1];
      Ast[acol + 0][arow] = v0.x; Ast[acol + 1][arow] = v0.y;
      Ast[acol + 2][arow] = v0.z; Ast[acol + 3][arow] = v0.w;
      Ast[acol + 4][arow] = v1.x; Ast[acol + 5][arow] = v1.y;
      Ast[acol + 6][arow] = v1.z; Ast[acol + 7][arow] = v1.w;
    }
    {   // B tile (1 float4 per thread, fully coalesced)
      *(float4*)&Bs[brow][bcol] =
          *(const float4*)(Bsrc + (size_t)(kb + brow) * 2048 + n0 + bcol);
    }
    __syncthreads();
    #pragma unroll
    for (int kk = 0; kk < 16; ++kk) {
      const float4 a0 = *(const float4*)&Ast[kk][ty * 4];
      const float4 a1 = *(const float4*)&Ast[kk][64 + ty * 4];
      const float4 b0 = *(const float4*)&Bs[kk][tx * 4];
      const float av[8] = {a0.x, a0.y, a0.z, a0.w, a1.x, a1.y, a1.z, a1.w};
      const float bv[4] = {b0.x, b0.y, b0.z, b0.w};
      #pragma unroll
      for (int i = 0; i < 8; ++i)
        #pragma unroll
        for (int j = 0; j < 4; ++j)
          acc[i][j] = __fmaf_rn(av[i], bv[j], acc[i][j]);
    }
  }
  float* dstz = part + (size_t)z * GSTRIDE + (size_t)m0 * 2048 + n0;
  #pragma unroll
  for (int i = 0; i < 8; ++i) {
    const int mr = ((i >> 2) << 6) + ty * 4 + (i & 3);
    *(float4*)(dstz + (size_t)mr * 2048 + tx * 4) =
        make_float4(acc[i][0], acc[i][1], acc[i][2], acc[i][3]);
  }
}

// fused: panel combine (strict left-to-right, == old k_combine chain) -> gate spikes
//        -> LSTM cell -> fc1 LIF -> fc2 LIF -> h2 accum
__global__ __launch_bounds__(256) void k_cell(
    const float* __restrict__ part, const float* __restrict__ bih, const float* __restrict__ bhh,
    float* __restrict__ lc, float* __restrict__ lh,
    const float* __restrict__ fc1W, const float* __restrict__ fc1b,
    const float* __restrict__ fc2W, const float* __restrict__ fc2b,
    float* __restrict__ h1_mem, float* __restrict__ h1_spk,
    float* __restrict__ h2_mem, float* __restrict__ h2_spk, float* __restrict__ h2_sum) {
  __shared__ float lhl[512];
  __shared__ float sp1l[256];
  const int s = blockIdx.x;
  const int p = threadIdx.x;
  #pragma unroll
  for (int half = 0; half < 2; ++half) {
    const int h = p + half * 256;
    float gv[4];
    #pragma unroll
    for (int g = 0; g < 4; ++g) {
      const int u = g * 512 + h;
      const float* pp = part + (size_t)s * 2048 + u;
      float tih = pp[0];
      #pragma unroll
      for (int zz = 1; zz < 22; ++zz) tih = __fadd_rn(tih, pp[(size_t)zz * GSTRIDE]);
      const float thh = __fadd_rn(pp[22u * GSTRIDE], pp[23u * GSTRIDE]);
      gv[g] = __fadd_rn(__fadd_rn(__fadd_rn(tih, bih[u]), thh), bhh[u]);
    }
    const float iv = gv[0] > 0.f ? 1.f : 0.f;
    const float fv = gv[1] > 0.f ? 1.f : 0.f;
    const float ggv = gv[2] > 0.f ? 1.f : 0.f;
    const float ov = gv[3] > 0.f ? 1.f : 0.f;
    const int li = s * 512 + h;
    const float lcv = __fadd_rn(__fmul_rn(fv, lc[li]), __fmul_rn(iv, ggv));
    lc[li] = lcv;
    const float lhv = __fmul_rn(lcv, ov);
    lh[li] = lhv;
    lhl[h] = lhv;
  }
  __syncthreads();
  float a0 = 0.f, a1 = 0.f;
  #pragma unroll 8
  for (int q = 0; q < 384; ++q) a0 = __fmaf_rn(lhl[q], fc1W[q * 256 + p], a0);
  #pragma unroll 8
  for (int q = 384; q < 512; ++q) a1 = __fmaf_rn(lhl[q], fc1W[q * 256 + p], a1);
  const float dot1 = __fadd_rn(a0, a1);
  const int i1 = s * 256 + p;
  const float m1 = h1_mem[i1], s1o = h1_spk[i1];
  const float nm1 = __fadd_rn(__fadd_rn(__fmul_rn(__fmul_rn(m1, 0.2f), __fsub_rn(1.f, s1o)), dot1), fc1b[p]);
  h1_mem[i1] = nm1;
  const float sp1 = nm1 > 0.5f ? 1.f : 0.f;
  h1_spk[i1] = sp1;
  sp1l[p] = sp1;
  __syncthreads();
  if (p < 4) {
    float acc = 0.f;
    for (int q = 0; q < 256; ++q) acc = __fmaf_rn(sp1l[q], fc2W[q * 4 + p], acc);
    const int i2 = s * 4 + p;
    const float m2 = h2_mem[i2], s2o = h2_spk[i2];
    const float nm2 = __fadd_rn(__fadd_rn(__fmul_rn(__fmul_rn(m2, 0.2f), __fsub_rn(1.f, s2o)), acc), fc2b[p]);
    h2_mem[i2] = nm2;
    const float sp2 = nm2 > 0.5f ? 1.f : 0.f;
    h2_spk[i2] = sp2;
    h2_sum[i2] = __fadd_rn(h2_sum[i2], sp2);
  }
}

__global__ void k_out(const float* __restrict__ h2_sum, float* __restrict__ out) {
  int i = blockIdx.x * 256 + threadIdx.x;
  if (i < SG * 4) out[i] = __fmul_rn(h2_sum[i], 0.03125f);
}

// ---------------- launch ----------------
extern "C" void kernel_launch(void* const* d_in, const int* in_sizes, int n_in,
                              void* d_out, int out_size, void* d_ws, size_t ws_size,
                              hipStream_t stream) {
  const float* x      = (const float*)d_in[0];
  const int*   ei     = (const int*)  d_in[1];
  const float* encW   = (const float*)d_in[2];
  const float* encB   = (const float*)d_in[3];
  const float* basesW = (const float*)d_in[4];
  const float* basesB = (const float*)d_in[5];
  const float* combW  = (const float*)d_in[6];
  const float* combB  = (const float*)d_in[7];
  const float* convB  = (const float*)d_in[8];
  const float* Wih    = (const float*)d_in[9];
  const float* Whh    = (const float*)d_in[10];
  const float* bih    = (const float*)d_in[11];
  const float* bhh    = (const float*)d_in[12];
  const float* fc1W   = (const float*)d_in[13];
  const float* fc1b   = (const float*)d_in[14];
  const float* fc2W   = (const float*)d_in[15];
  const float* fc2b   = (const float*)d_in[16];

  float* ws = (float*)d_ws;
  float* enc_mem = ws + OFF_ENC_MEM;
  float* enc_spk = ws + OFF_ENC_SPK;
  float* c1_mem  = ws + OFF_C1_MEM;
  float* c1_spk  = ws + OFF_C1_SPK;   // xl
  float* lhp     = ws + OFF_LH;
  float* lcp     = ws + OFF_LC;
  float* h1_mem  = ws + OFF_H1_MEM;
  float* h1_spk  = ws + OFF_H1_SPK;
  float* h2_mem  = ws + OFF_H2_MEM;
  float* h2_spk  = ws + OFF_H2_SPK;
  float* h2_sum  = ws + OFF_H2_SUM;
  float* bases   = ws + OFF_BASES;
  float* comb    = ws + OFF_COMB;
  float* partp   = ws + OFF_PART;
  float* dinv    = ws + OFF_DINV;
  float* colw    = ws + OFF_COLW;
  int* ibase = (int*)((char*)d_ws + (size_t)FLOAT_END * 4);
  int* deg  = ibase + IOFF_DEG;
  int* fill = ibase + IOFF_FILL;
  int* rowp = ibase + IOFF_ROWPTR;
  int* eid  = ibase + IOFF_EID;
  int* col  = ibase + IOFF_COL;

  hipMemsetAsync(ws, 0, (size_t)ZERO_FLOATS * 4, stream);
  hipMemsetAsync(ibase, 0, 32768 * 4, stream);

  k_deg    <<<NE / 256, 256, 0, stream>>>(ei, deg);
  k_dinv   <<<NN / 256, 256, 0, stream>>>(deg, dinv);
  k_scan   <<<1, 1024, 0, stream>>>(deg, rowp);
  k_scatter<<<NE / 256, 256, 0, stream>>>(ei, rowp, fill, eid);
  k_sortadj<<<NN / 256, 256, 0, stream>>>(rowp, eid, ei, dinv, col, colw);

  for (int t = 0; t < TSTEPS; ++t) {
    k_enc       <<<NN / 2, 256, 0, stream>>>(x, encW, encB, enc_mem, enc_spk, t);
    k_bases_comb<<<NN / 64, 256, 0, stream>>>(enc_spk, basesW, basesB, combW, combB, bases, comb);
    k_aggconv   <<<NN / 4, 256, 0, stream>>>(bases, comb, dinv, rowp, col, colw, convB, c1_mem, c1_spk);
    k_gpanel    <<<dim3(32, 2, NPANEL), 256, 0, stream>>>(c1_spk, lhp, Wih, Whh, partp);
    k_cell      <<<SG, 256, 0, stream>>>(partp, bih, bhh, lcp, lhp, fc1W, fc1b, fc2W, fc2b,
                                         h1_mem, h1_spk, h2_mem, h2_spk, h2_sum);
  }
  k_out<<<4, 256, 0, stream>>>(h2_sum, (float*)d_out);
}